// Round 8
// baseline (927.662 us; speedup 1.0000x reference)
//
// Round-8: dispatch-count reduction via cooperative grid-sync chain.
// 4 dispatches: prep -> mega1(g1+batch sk/ck) -> coop(g2,g3,g4,task) -> final.
// All math bodies verbatim from proven rounds (bitwise-identical outputs).
// Fallback: if cooperative launch fails, enqueue the 4 proven standalone
// dispatches instead (correctness preserved, perf ~= round 7).
#include <hip/hip_runtime.h>
#include <hip/hip_bf16.h>
#include <hip/hip_cooperative_groups.h>
#include <math.h>

namespace cg = cooperative_groups;

#define BNEPS 1e-5f
#define BDIM_B 128
#define CDIM 512
#define SS 121
#define KK 9
#define MROWS (BDIM_B * SS)   // 15488

typedef unsigned short u16;
typedef __bf16 bf16x8 __attribute__((ext_vector_type(8)));
typedef float f32x4 __attribute__((ext_vector_type(4)));

__device__ __forceinline__ u16 f2bf(float f) {
    union { float f; unsigned int u; } v; v.f = f;
    unsigned int r = v.u + 0x7FFF + ((v.u >> 16) & 1);   // RNE
    return (u16)(r >> 16);
}
__device__ __forceinline__ float bf2f(u16 v) {
    union { unsigned int u; float f; } x; x.u = ((unsigned int)v) << 16; return x.f;
}

__device__ __forceinline__ void gld16(const u16* g, u16* l) {
    __builtin_amdgcn_global_load_lds(
        (const __attribute__((address_space(1))) void*)g,
        (__attribute__((address_space(3))) void*)l, 16, 0, 0);
}

// ---------------------------------------------------------------------------
// 128x128 BK=64 MFMA GEMM body (round-0 proven: ~50us @K=1024 grid 968).
// Shared memory passed in (AlsB/BlsB each 2*128*32 u16) so callers can unify
// LDS across fused phases. Grid mapping = the proven 968-block XCD swizzle.
// MODE 1: relu -> bf16, p-major remap Y[(m%121)*128 + m/121][n]
// MODE 2: block rows all one p (= bx); relu, reduce 128 rows -> bf16
// ---------------------------------------------------------------------------
template<int MODE>
__device__ __forceinline__ void gemm128_body(
    const u16* __restrict__ A, const u16* __restrict__ Bw,
    const float* __restrict__ bias, const float* __restrict__ g,
    const float* __restrict__ bb, void* __restrict__ out,
    int Kd, int N, int bi, u16* AlsB, u16* BlsB)
{
    const int tid  = threadIdx.x;
    const int lane = tid & 63;
    const int w    = tid >> 6;
    const int wm   = w >> 1, wn = w & 1;

    int bx, by;
    {
        int i = bi;
        if (i < 960) {
            int xg = i & 7;
            int j  = i >> 3;
            bx = xg * 15 + (j >> 3);
            by = j & 7;
        } else { bx = 120; by = i - 960; }
    }
    const int bm = bx * 128;
    const int bn = by * 128;

    f32x4 acc[4][4] = {};

    const int subrow = tid >> 2;
    const int kq     = tid & 3;
    const int gchunk = kq ^ ((subrow >> 1) & 3);
    const u16* Ab = A  + (size_t)(bm + subrow) * Kd + gchunk * 8;
    const u16* Bb = Bw + (size_t)(bn + subrow) * Kd + gchunk * 8;
    u16* Al0  = AlsB + (w * 16) * 32;
    u16* Al1  = AlsB + (w * 16 + 64) * 32;
    u16* Bl0  = BlsB + (w * 16) * 32;
    u16* Bl1  = BlsB + (w * 16 + 64) * 32;
    u16* Al0b = AlsB + 4096 + (w * 16) * 32;
    u16* Al1b = AlsB + 4096 + (w * 16 + 64) * 32;
    u16* Bl0b = BlsB + 4096 + (w * 16) * 32;
    u16* Bl1b = BlsB + 4096 + (w * 16 + 64) * 32;

    const int fa_row = wm * 64 + (lane & 15);
    const int fb_row = wn * 64 + (lane & 15);
    const int kofs   = (((lane >> 4) ^ (((lane & 15) >> 1) & 3))) * 8;

    for (int k0 = 0; k0 < Kd; k0 += 64) {
        __syncthreads();
        gld16(Ab + k0,                      Al0);
        gld16(Ab + (size_t)64 * Kd + k0,    Al1);
        gld16(Bb + k0,                      Bl0);
        gld16(Bb + (size_t)64 * Kd + k0,    Bl1);
        gld16(Ab + k0 + 32,                 Al0b);
        gld16(Ab + (size_t)64 * Kd + k0 + 32, Al1b);
        gld16(Bb + k0 + 32,                 Bl0b);
        gld16(Bb + (size_t)64 * Kd + k0 + 32, Bl1b);
        __syncthreads();

        #pragma unroll
        for (int hb = 0; hb < 2; ++hb) {
            const u16* Ah = AlsB + hb * 4096;
            const u16* Bh = BlsB + hb * 4096;
            bf16x8 af[4], bfv[4];
            #pragma unroll
            for (int i = 0; i < 4; ++i)
                af[i] = *(const bf16x8*)&Ah[(fa_row + i * 16) * 32 + kofs];
            #pragma unroll
            for (int j = 0; j < 4; ++j)
                bfv[j] = *(const bf16x8*)&Bh[(fb_row + j * 16) * 32 + kofs];
            #pragma unroll
            for (int i = 0; i < 4; ++i)
                #pragma unroll
                for (int j = 0; j < 4; ++j)
                    acc[i][j] = __builtin_amdgcn_mfma_f32_16x16x32_bf16(af[i], bfv[j], acc[i][j], 0, 0, 0);
        }
    }

    const float inv = 1.0f / sqrtf(1.0f + BNEPS);

    if (MODE == 1) {
        u16* Y = (u16*)out;
        int dstrow[4][4];
        #pragma unroll
        for (int i = 0; i < 4; ++i) {
            int mb = bm + wm * 64 + i * 16 + (lane >> 4) * 4;
            #pragma unroll
            for (int r = 0; r < 4; ++r) {
                int m = mb + r;
                int b = m / 121, p = m - b * 121;
                dstrow[i][r] = p * 128 + b;
            }
        }
        #pragma unroll
        for (int j = 0; j < 4; ++j) {
            int n = bn + wn * 64 + j * 16 + (lane & 15);
            float sc = g[n] * inv, bo = bias[n], bv = bb[n];
            #pragma unroll
            for (int i = 0; i < 4; ++i)
                #pragma unroll
                for (int r = 0; r < 4; ++r) {
                    float v = (acc[i][j][r] + bo) * sc + bv;
                    v = fmaxf(v, 0.0f);
                    Y[(size_t)dstrow[i][r] * N + n] = f2bf(v);
                }
        }
    } else {
        float ps[4];
        #pragma unroll
        for (int j = 0; j < 4; ++j) {
            int n = bn + wn * 64 + j * 16 + (lane & 15);
            float sc = g[n] * inv, bo = bias[n], bv = bb[n];
            float s = 0.f;
            #pragma unroll
            for (int i = 0; i < 4; ++i)
                #pragma unroll
                for (int r = 0; r < 4; ++r) {
                    float v = (acc[i][j][r] + bo) * sc + bv;
                    s += fmaxf(v, 0.0f);
                }
            ps[j] = s;
        }
        __syncthreads();
        float* red = (float*)AlsB;
        #pragma unroll
        for (int j = 0; j < 4; ++j)
            red[(wm * 4 + (lane >> 4)) * 128 + wn * 64 + j * 16 + (lane & 15)] = ps[j];
        __syncthreads();
        if (tid < 128) {
            float s = 0.f;
            #pragma unroll
            for (int r = 0; r < 8; ++r) s += red[r * 128 + tid];
            ((u16*)out)[(size_t)bx * N + bn + tid] = f2bf(s);
        }
    }
}

// ---------------------------------------------------------------------------
// barrier-free small GEMM body (M=128), 32-col blocks (round-7 proven).
// MODE 3: relu; MODE 4: sigmoid. Y[m*N+n] bf16. No LDS, no barriers.
// ---------------------------------------------------------------------------
template<int MODE>
__device__ __forceinline__ void gemm_small_body(
    const u16* __restrict__ A, const u16* __restrict__ Bw,
    const float* __restrict__ bias, const float* __restrict__ g,
    const float* __restrict__ bb, u16* __restrict__ Y,
    int Kd, int N, int bn)
{
    const int tid  = threadIdx.x;
    const int lane = tid & 63;
    const int w    = tid >> 6;
    const int fr   = lane & 15;
    const int kq   = lane >> 4;
    const int r0   = w * 32;

    f32x4 acc[2][2] = {};
    const u16* a0p = A + (size_t)(r0 + fr) * Kd + kq * 8;
    const u16* a1p = a0p + (size_t)16 * Kd;
    const u16* b0p = Bw + (size_t)(bn + fr) * Kd + kq * 8;
    const u16* b1p = b0p + (size_t)16 * Kd;

    #pragma unroll 4
    for (int k0 = 0; k0 < Kd; k0 += 32) {
        bf16x8 a0 = *(const bf16x8*)(a0p + k0);
        bf16x8 a1 = *(const bf16x8*)(a1p + k0);
        bf16x8 b0 = *(const bf16x8*)(b0p + k0);
        bf16x8 b1 = *(const bf16x8*)(b1p + k0);
        acc[0][0] = __builtin_amdgcn_mfma_f32_16x16x32_bf16(a0, b0, acc[0][0], 0, 0, 0);
        acc[0][1] = __builtin_amdgcn_mfma_f32_16x16x32_bf16(a0, b1, acc[0][1], 0, 0, 0);
        acc[1][0] = __builtin_amdgcn_mfma_f32_16x16x32_bf16(a1, b0, acc[1][0], 0, 0, 0);
        acc[1][1] = __builtin_amdgcn_mfma_f32_16x16x32_bf16(a1, b1, acc[1][1], 0, 0, 0);
    }

    const float inv = 1.0f / sqrtf(1.0f + BNEPS);
    #pragma unroll
    for (int j = 0; j < 2; ++j) {
        int n = bn + j * 16 + (lane & 15);
        float sc = g[n] * inv, bo = bias[n], bv = bb[n];
        #pragma unroll
        for (int t = 0; t < 2; ++t)
            #pragma unroll
            for (int r = 0; r < 4; ++r) {
                int m = r0 + t * 16 + (lane >> 4) * 4 + r;
                float v = (acc[t][j][r] + bo) * sc + bv;
                if (MODE == 3) v = fmaxf(v, 0.0f);
                else           v = 1.f / (1.f + expf(-v));
                Y[(size_t)m * N + n] = f2bf(v);
            }
    }
}

// ---------------------------------------------------------------------------
// spatial kernel body (proven): 128-row MFMA GEMM vs wcb (16x512, L1-hot).
// ---------------------------------------------------------------------------
__device__ __forceinline__ void spatial_body(
    const u16* __restrict__ Arow, const u16* __restrict__ wcb,
    const float* __restrict__ b_conv, const float* __restrict__ g_sp,
    const float* __restrict__ b_sp, float* __restrict__ skb,
    bool task, int blk, float* __restrict__ skt)
{
    const float inv = 1.0f / sqrtf(1.0f + BNEPS);
    const int lane = threadIdx.x & 63;
    const int w    = threadIdx.x >> 6;
    const int fr   = lane & 15;
    const int kq   = lane >> 4;
    const int r0   = w * 32;

    f32x4 acc0 = {}, acc1 = {};
    const u16* a0p = Arow + (size_t)(r0 + fr) * 512 + kq * 8;
    const u16* a1p = a0p + (size_t)16 * 512;
    const u16* bp  = wcb + (size_t)fr * 512 + kq * 8;
    #pragma unroll
    for (int k0 = 0; k0 < 512; k0 += 32) {
        bf16x8 a0 = *(const bf16x8*)(a0p + k0);
        bf16x8 a1 = *(const bf16x8*)(a1p + k0);
        bf16x8 b  = *(const bf16x8*)(bp + k0);
        acc0 = __builtin_amdgcn_mfma_f32_16x16x32_bf16(a0, b, acc0, 0, 0, 0);
        acc1 = __builtin_amdgcn_mfma_f32_16x16x32_bf16(a1, b, acc1, 0, 0, 0);
    }

    int n = lane & 15;
    if (n < 9) {
        float bo = b_conv[n];
        #pragma unroll
        for (int t = 0; t < 2; ++t) {
            f32x4 a = t ? acc1 : acc0;
            #pragma unroll
            for (int r = 0; r < 4; ++r) {
                int mloc = r0 + t * 16 + (lane >> 4) * 4 + r;
                if (!task) {
                    int m = blk * 128 + mloc;
                    int p = m % 121;
                    float v = (a[r] + bo) * (g_sp[p] * inv) + b_sp[p];
                    skb[(size_t)m * 9 + n] = v;
                } else if (mloc < 121) {
                    float v = (a[r] + bo) * (g_sp[mloc] * inv) + b_sp[mloc];
                    skt[(size_t)mloc * 9 + n] = v;
                }
            }
        }
    }
}

// ---------------------------------------------------------------------------
// channel chain body (proven): DCT pool (2c/thread) -> fc1 -> fc2+sig+BN.
// ---------------------------------------------------------------------------
__device__ __forceinline__ void channel_body(
    const u16* __restrict__ src, const float* __restrict__ dctT,
    const float* __restrict__ fc1, const float* __restrict__ fc2,
    const float* __restrict__ g_ch, const float* __restrict__ b_ch,
    float* __restrict__ outp, float* yls, float* y2ls)
{
    const float inv = 1.0f / sqrtf(1.0f + BNEPS);

    {
        int c = threadIdx.x * 2;
        float s0 = 0.f, s1 = 0.f;
        for (int p = 0; p < SS; ++p) {
            unsigned v = *(const unsigned*)(src + (size_t)p * 512 + c);
            float2 d  = *(const float2*)(dctT + (size_t)p * 512 + c);
            s0 += bf2f((u16)(v & 0xFFFFu)) * d.x;
            s1 += bf2f((u16)(v >> 16)) * d.y;
        }
        yls[c] = s0; yls[c + 1] = s1;
    }
    __syncthreads();

    {
        int o = threadIdx.x >> 3, kp = threadIdx.x & 7;
        const float* w = fc1 + (size_t)o * 512;
        float s = 0.f;
        for (int k = kp * 4; k < 512; k += 32) {
            float4 wv = *(const float4*)(w + k);
            float4 av = *(const float4*)(yls + k);
            s += wv.x * av.x + wv.y * av.y + wv.z * av.z + wv.w * av.w;
        }
        s += __shfl_xor(s, 1);
        s += __shfl_xor(s, 2);
        s += __shfl_xor(s, 4);
        if (kp == 0) y2ls[o] = fmaxf(s, 0.f);
    }
    __syncthreads();

    for (int o = threadIdx.x; o < CDIM * KK; o += 256) {
        const float* w = fc2 + (size_t)o * 32;
        float s = 0.f;
        #pragma unroll
        for (int k = 0; k < 32; ++k) s += y2ls[k] * w[k];
        s = 1.f / (1.f + expf(-s));
        int c = o / KK;
        s = s * (g_ch[c] * inv) + b_ch[c];
        outp[o] = s;
    }
}

// ---------------------------------------------------------------------------
// mega1 (round-6 proven-correct): blocks [0,968) g1 GEMM; [968,1089) batch
// spatial; [1089,1217) batch channel. All depend only on prep.
// ---------------------------------------------------------------------------
__global__ __launch_bounds__(256)
void mega1(const u16* __restrict__ Xb, const u16* __restrict__ w1b,
           const float* __restrict__ up_b1, const float* __restrict__ up_g1,
           const float* __restrict__ up_bb1, u16* __restrict__ Y1,
           const u16* __restrict__ wcb, const float* __restrict__ b_conv,
           const float* __restrict__ g_sp, const float* __restrict__ b_sp,
           const float* __restrict__ dctT,
           const float* __restrict__ fc1, const float* __restrict__ fc2,
           const float* __restrict__ g_ch, const float* __restrict__ b_ch,
           float* __restrict__ skb, float* __restrict__ ckbuf)
{
    __shared__ __align__(16) u16 shmem[4][128 * 32];
    int bi = blockIdx.x;
    if (bi < 968) {
        gemm128_body<1>(Xb, w1b, up_b1, up_g1, up_bb1, (void*)Y1, 512, 1024, bi,
                        &shmem[0][0], &shmem[2][0]);
        return;
    }
    bi -= 968;
    if (bi < 121) {
        spatial_body(Xb + (size_t)bi * 128 * 512, wcb, b_conv, g_sp, b_sp,
                     skb, false, bi, nullptr);
        return;
    }
    bi -= 121;   // 0..127
    float* sm = (float*)&shmem[0][0];
    channel_body(Xb + (size_t)bi * 121 * 512, dctT, fc1, fc2, g_ch, b_ch,
                 ckbuf + (size_t)bi * CDIM * KK, sm, sm + 512);
}

// ---------------------------------------------------------------------------
// cooperative chain: g2 (968 blocks) -> g3 (32) -> g4 (16) -> task (2),
// separated by __threadfence + grid.sync (sanctioned grid-wide barrier).
// __launch_bounds__(256,4): VGPR<=128 -> 4 blocks/CU -> 1024 slots >= 968.
// LDS 32KB static (shared across phases; phases are sync-separated).
// ---------------------------------------------------------------------------
__global__ __launch_bounds__(256, 4)
void coop_chain(const u16* __restrict__ Y1, const u16* __restrict__ w2b,
                const float* __restrict__ up_b2, const float* __restrict__ up_g2,
                const float* __restrict__ up_bb2, u16* __restrict__ asum_b,
                const u16* __restrict__ lw1b,
                const float* __restrict__ lo_b1, const float* __restrict__ lo_g1,
                const float* __restrict__ lo_bb1, u16* __restrict__ a3b,
                const u16* __restrict__ lw2b,
                const float* __restrict__ lo_b2, const float* __restrict__ lo_g2,
                const float* __restrict__ lo_bb2, u16* __restrict__ ts_pc,
                const u16* __restrict__ wcb, const float* __restrict__ b_conv,
                const float* __restrict__ g_sp, const float* __restrict__ b_sp,
                const float* __restrict__ dctT,
                const float* __restrict__ fc1, const float* __restrict__ fc2,
                const float* __restrict__ g_ch, const float* __restrict__ b_ch,
                float* __restrict__ skt, float* __restrict__ ck_t)
{
    __shared__ __align__(16) u16 shmem[4][128 * 32];
    cg::grid_group grid = cg::this_grid();

    // phase A: g2 (all 968 blocks)
    gemm128_body<2>(Y1, w2b, up_b2, up_g2, up_bb2, (void*)asum_b, 1024, 1024,
                    blockIdx.x, &shmem[0][0], &shmem[2][0]);
    __threadfence();
    grid.sync();

    // phase B: g3 (32 blocks x 32 cols)
    if (blockIdx.x < 32)
        gemm_small_body<3>(asum_b, lw1b, lo_b1, lo_g1, lo_bb1, a3b, 1024, 1024,
                           blockIdx.x * 32);
    __threadfence();
    grid.sync();

    // phase C: g4 (16 blocks x 32 cols)
    if (blockIdx.x < 16)
        gemm_small_body<4>(a3b, lw2b, lo_b2, lo_g2, lo_bb2, ts_pc, 1024, 512,
                           blockIdx.x * 32);
    __threadfence();
    grid.sync();

    // phase D: task spatial (block 0) + task channel (block 1)
    if (blockIdx.x == 0) {
        spatial_body(ts_pc, wcb, b_conv, g_sp, b_sp, nullptr, true, 0, skt);
    } else if (blockIdx.x == 1) {
        float* sm = (float*)&shmem[0][0];
        channel_body(ts_pc, dctT, fc1, fc2, g_ch, b_ch, ck_t, sm, sm + 512);
    }
}

// ---------------------------------------------------------------------------
// fallback standalone kernels (proven) — used only if coop launch fails.
// ---------------------------------------------------------------------------
template<int MODE>
__global__ __launch_bounds__(256)
void gemm_mfma(const u16* __restrict__ A, const u16* __restrict__ Bw,
               const float* __restrict__ bias, const float* __restrict__ g,
               const float* __restrict__ bb, void* __restrict__ out,
               int Kd, int N)
{
    __shared__ __align__(16) u16 shmem[4][128 * 32];
    gemm128_body<MODE>(A, Bw, bias, g, bb, out, Kd, N, blockIdx.x,
                       &shmem[0][0], &shmem[2][0]);
}

template<int MODE>
__global__ __launch_bounds__(256)
void gemm_small(const u16* __restrict__ A, const u16* __restrict__ Bw,
                const float* __restrict__ bias, const float* __restrict__ g,
                const float* __restrict__ bb, u16* __restrict__ Y,
                int Kd, int N)
{
    gemm_small_body<MODE>(A, Bw, bias, g, bb, Y, Kd, N, blockIdx.x * 32);
}

__global__ __launch_bounds__(256)
void task_combo(const u16* __restrict__ ts_pc, const u16* __restrict__ wcb,
                const float* __restrict__ b_conv, const float* __restrict__ g_sp,
                const float* __restrict__ b_sp, const float* __restrict__ dctT,
                const float* __restrict__ fc1, const float* __restrict__ fc2,
                const float* __restrict__ g_ch, const float* __restrict__ b_ch,
                float* __restrict__ skt, float* __restrict__ ck_t)
{
    __shared__ float sm[544];
    if (blockIdx.x == 0)
        spatial_body(ts_pc, wcb, b_conv, g_sp, b_sp, nullptr, true, 0, skt);
    else
        channel_body(ts_pc, dctT, fc1, fc2, g_ch, b_ch, ck_t, sm, sm + 512);
}

// ---------------------------------------------------------------------------
// prep combo (proven): x transpose + vectorized weight casts + dct transpose
// + w_conv pad.
// ---------------------------------------------------------------------------
#define W1N (1024 * 512)
#define W2N (1024 * 1024)
#define L1N (1024 * 1024)
#define L2N (512 * 1024)
#define VECN ((W1N + W2N + L1N + L2N) / 4)   // 786432 quads
#define DCTN (512 * 121)
#define WCN (16 * 512)
#define PREP_ELEM (VECN + DCTN + WCN)
#define PREP_BLKS (1024 + (PREP_ELEM + 255) / 256)
__global__ void prep_combo(const float* __restrict__ x, u16* __restrict__ Xb,
                           const float* __restrict__ w1, const float* __restrict__ w2,
                           const float* __restrict__ l1, const float* __restrict__ l2,
                           const float* __restrict__ dct, const float* __restrict__ w_conv,
                           u16* __restrict__ o1, u16* __restrict__ o2,
                           u16* __restrict__ o3, u16* __restrict__ o4,
                           float* __restrict__ dctT, u16* __restrict__ wcb)
{
    __shared__ float t[64 * 121];
    if (blockIdx.x < 1024) {
        int b = blockIdx.x >> 3, c0 = (blockIdx.x & 7) * 64;
        for (int idx = threadIdx.x; idx < 64 * 121; idx += 256) {
            int c = idx / 121, p = idx - c * 121;
            t[idx] = x[((size_t)b * 512 + c0 + c) * 121 + p];
        }
        __syncthreads();
        for (int idx = threadIdx.x; idx < 121 * 64; idx += 256) {
            int p = idx >> 6, c = idx & 63;
            Xb[((size_t)(b * 121 + p)) * 512 + c0 + c] = f2bf(t[c * 121 + p]);
        }
        return;
    }
    int i = (blockIdx.x - 1024) * 256 + threadIdx.x;
    if (i < VECN) {
        int q = i;
        const float* s; u16* d;
        if (q < W1N / 4)                    { s = w1; d = o1; }
        else if (q < (W1N + W2N) / 4)       { s = w2; d = o2; q -= W1N / 4; }
        else if (q < (W1N + W2N + L1N) / 4) { s = l1; d = o3; q -= (W1N + W2N) / 4; }
        else                                { s = l2; d = o4; q -= (W1N + W2N + L1N) / 4; }
        float4 v = ((const float4*)s)[q];
        uint2 r;
        r.x = (unsigned)f2bf(v.x) | ((unsigned)f2bf(v.y) << 16);
        r.y = (unsigned)f2bf(v.z) | ((unsigned)f2bf(v.w) << 16);
        ((uint2*)d)[q] = r;
        return;
    }
    i -= VECN;
    if (i < DCTN) {
        int p = i >> 9, c = i & 511;
        dctT[i] = dct[(size_t)c * 121 + p];
        return;
    }
    i -= DCTN;
    if (i < WCN) {
        int n = i >> 9, c = i & 511;
        wcb[i] = (n < 9) ? f2bf(w_conv[(size_t)n * 512 + c]) : (u16)0;
    }
}

// ---------------------------------------------------------------------------
// final combo (vectorized, proven).
// ---------------------------------------------------------------------------
#define TKN (CDIM * SS * KK)              // 557568
#define FIN_BLKS (1024 + (TKN + 255) / 256)
__global__ __launch_bounds__(256)
void final_combo(const float* __restrict__ x, const float* __restrict__ skb,
                 const float* __restrict__ sk_t, const float* __restrict__ ckbuf,
                 const float* __restrict__ ck_t, float* __restrict__ out0,
                 float* __restrict__ tk)
{
    __shared__ float PS[SS * KK];
    __shared__ float CS[64 * KK];
    __shared__ float XT[64 * SS];

    if (blockIdx.x >= 1024) {
        int idx = (blockIdx.x - 1024) * 256 + threadIdx.x;
        if (idx < TKN) {
            int k9 = idx % KK;
            int pc = idx / KK;
            int p = pc % SS, c = pc / SS;
            tk[idx] = sk_t[p * KK + k9] * ck_t[c * KK + k9];
        }
        return;
    }

    const int tid = threadIdx.x;
    const int b = blockIdx.x >> 3, c0 = (blockIdx.x & 7) * 64;

    const float* sp = skb + (size_t)b * SS * KK;
    for (int i = tid; i < SS * KK; i += 256) PS[i] = sp[i] * sk_t[i];
    const float* cp = ckbuf + ((size_t)b * CDIM + c0) * KK;
    const float* tp = ck_t + (size_t)c0 * KK;
    for (int i = tid; i < (64 * KK) / 4; i += 256) {
        float4 a = ((const float4*)cp)[i];
        float4 bq = ((const float4*)tp)[i];
        float4 r; r.x = a.x * bq.x; r.y = a.y * bq.y; r.z = a.z * bq.z; r.w = a.w * bq.w;
        ((float4*)CS)[i] = r;
    }
    const float* xp = x + ((size_t)b * CDIM + c0) * SS;
    for (int i = tid; i < (64 * SS) / 4; i += 256)
        ((float4*)XT)[i] = ((const float4*)xp)[i];
    __syncthreads();

    float* op = out0 + ((size_t)b * CDIM + c0) * SS;
    for (int ci = tid; ci < (64 * SS) / 4; ci += 256) {
        float4 o;
        #pragma unroll
        for (int r = 0; r < 4; ++r) {
            int i = ci * 4 + r;
            int c = i / SS, p = i - c * SS;
            int h = p / 11, w = p - h * 11;
            const float* xc = XT + c * SS;
            const float* ps = PS + p * KK;
            const float* cs = CS + c * KK;
            float acc = 0.f;
            #pragma unroll
            for (int di = 0; di < 3; ++di) {
                int hh = h + di - 1;
                bool hv = (unsigned)hh < 11u;
                #pragma unroll
                for (int dj = 0; dj < 3; ++dj) {
                    int ww = w + dj - 1;
                    int k = di * 3 + dj;
                    float xv = (hv && (unsigned)ww < 11u) ? xc[hh * 11 + ww] : 0.f;
                    acc += xv * ps[k] * cs[k];
                }
            }
            ((float*)&o)[r] = acc * (1.0f / 9.0f) + xc[p];
        }
        ((float4*)op)[ci] = o;
    }
}

extern "C" void kernel_launch(void* const* d_in, const int* in_sizes, int n_in,
                              void* d_out, int out_size, void* d_ws, size_t ws_size,
                              hipStream_t stream)
{
    const float* x      = (const float*)d_in[0];
    const float* dct_w  = (const float*)d_in[1];
    const float* w_conv = (const float*)d_in[2];
    const float* b_conv = (const float*)d_in[3];
    const float* g_sp   = (const float*)d_in[4];
    const float* b_sp   = (const float*)d_in[5];
    const float* g_ch   = (const float*)d_in[6];
    const float* b_ch   = (const float*)d_in[7];
    const float* fc1    = (const float*)d_in[8];
    const float* fc2    = (const float*)d_in[9];
    const float* up_w1  = (const float*)d_in[10];
    const float* up_b1  = (const float*)d_in[11];
    const float* up_g1  = (const float*)d_in[12];
    const float* up_bb1 = (const float*)d_in[13];
    const float* up_w2  = (const float*)d_in[14];
    const float* up_b2  = (const float*)d_in[15];
    const float* up_g2  = (const float*)d_in[16];
    const float* up_bb2 = (const float*)d_in[17];
    const float* lo_w1  = (const float*)d_in[18];
    const float* lo_b1  = (const float*)d_in[19];
    const float* lo_g1  = (const float*)d_in[20];
    const float* lo_bb1 = (const float*)d_in[21];
    const float* lo_w2  = (const float*)d_in[22];
    const float* lo_b2  = (const float*)d_in[23];
    const float* lo_g2  = (const float*)d_in[24];
    const float* lo_bb2 = (const float*)d_in[25];

    float* out0 = (float*)d_out;                       // (B,C,11,11)
    float* tk   = out0 + (size_t)BDIM_B * CDIM * SS;   // (1,C,11,11,3,3)

    // workspace layout (bytes, 64B-aligned chunks)
    char* ws = (char*)d_ws;
    size_t off = 0;
    auto alloc = [&](size_t bytes) { void* p = ws + off; off += (bytes + 63) & ~(size_t)63; return p; };
    u16*   Xb      = (u16*)alloc((size_t)MROWS * 512 * 2);
    u16*   Y1      = (u16*)alloc((size_t)MROWS * 1024 * 2);
    u16*   w1b     = (u16*)alloc((size_t)W1N * 2);
    u16*   w2b     = (u16*)alloc((size_t)W2N * 2);
    u16*   lw1b    = (u16*)alloc((size_t)L1N * 2);
    u16*   lw2b    = (u16*)alloc((size_t)L2N * 2);
    u16*   asum_b  = (u16*)alloc((size_t)128 * 1024 * 2);   // rows 121..127 unwritten
    u16*   a3b     = (u16*)alloc((size_t)128 * 1024 * 2);
    u16*   ts_pc   = (u16*)alloc((size_t)128 * 512 * 2);    // task_s (p,c) bf16
    float* dctT    = (float*)alloc((size_t)SS * 512 * 4);
    u16*   wcb     = (u16*)alloc((size_t)WCN * 2);          // w_conv bf16 16x512 (pad)
    float* ckbuf   = (float*)alloc((size_t)BDIM_B * CDIM * KK * 4);
    float* skbuf   = (float*)alloc((size_t)BDIM_B * SS * KK * 4);
    float* ck_t    = (float*)alloc((size_t)CDIM * KK * 4);
    float* sk_t    = (float*)alloc((size_t)SS * KK * 4);

    // --- 1. prep: x transpose + weight casts + dct transpose ---
    hipLaunchKernelGGL(prep_combo, dim3(PREP_BLKS), dim3(256), 0, stream,
                       x, Xb, up_w1, up_w2, lo_w1, lo_w2, dct_w, w_conv,
                       w1b, w2b, lw1b, lw2b, dctT, wcb);

    // --- 2. mega1: g1 GEMM + batch spatial + batch channel (1217 blocks) ---
    hipLaunchKernelGGL(mega1, dim3(968 + 121 + 128), dim3(256), 0, stream,
                       Xb, w1b, up_b1, up_g1, up_bb1, Y1,
                       wcb, b_conv, g_sp, b_sp,
                       dctT, fc1, fc2, g_ch, b_ch,
                       skbuf, ckbuf);

    // --- 3. cooperative chain: g2 -> g3 -> g4 -> task (one dispatch) ---
    {
        const u16* aY1 = Y1;       const u16* aw2b = w2b;
        const float* ab2 = up_b2;  const float* ag2 = up_g2;  const float* abb2 = up_bb2;
        u16* aasum = asum_b;
        const u16* alw1 = lw1b;
        const float* alb1 = lo_b1; const float* alg1 = lo_g1; const float* albb1 = lo_bb1;
        u16* aa3 = a3b;
        const u16* alw2 = lw2b;
        const float* alb2 = lo_b2; const float* alg2 = lo_g2; const float* albb2 = lo_bb2;
        u16* ats = ts_pc;
        const u16* awcb = wcb;     const float* abconv = b_conv;
        const float* agsp = g_sp;  const float* absp = b_sp;
        const float* adctT = dctT; const float* afc1 = fc1;   const float* afc2 = fc2;
        const float* agch = g_ch;  const float* abch = b_ch;
        float* askt = sk_t;        float* ackt = ck_t;

        void* coopArgs[] = {
            (void*)&aY1, (void*)&aw2b, (void*)&ab2, (void*)&ag2, (void*)&abb2,
            (void*)&aasum,
            (void*)&alw1, (void*)&alb1, (void*)&alg1, (void*)&albb1, (void*)&aa3,
            (void*)&alw2, (void*)&alb2, (void*)&alg2, (void*)&albb2, (void*)&ats,
            (void*)&awcb, (void*)&abconv, (void*)&agsp, (void*)&absp,
            (void*)&adctT, (void*)&afc1, (void*)&afc2, (void*)&agch, (void*)&abch,
            (void*)&askt, (void*)&ackt
        };
        hipError_t e = hipLaunchCooperativeKernel(
            reinterpret_cast<void*>(&coop_chain), dim3(968), dim3(256),
            coopArgs, 0, stream);
        if (e != hipSuccess) {
            // fallback: proven standalone chain (perf ~= round 7)
            hipLaunchKernelGGL((gemm_mfma<2>), dim3(968), dim3(256), 0, stream,
                               Y1, w2b, up_b2, up_g2, up_bb2, (void*)asum_b, 1024, 1024);
            hipLaunchKernelGGL((gemm_small<3>), dim3(32), dim3(256), 0, stream,
                               asum_b, lw1b, lo_b1, lo_g1, lo_bb1, a3b, 1024, 1024);
            hipLaunchKernelGGL((gemm_small<4>), dim3(16), dim3(256), 0, stream,
                               a3b, lw2b, lo_b2, lo_g2, lo_bb2, ts_pc, 1024, 512);
            hipLaunchKernelGGL(task_combo, dim3(2), dim3(256), 0, stream,
                               ts_pc, wcb, b_conv, g_sp, b_sp,
                               dctT, fc1, fc2, g_ch, b_ch, sk_t, ck_t);
        }
    }

    // --- 4. final fused + task-kernel write ---
    hipLaunchKernelGGL(final_combo, dim3(FIN_BLKS), dim3(256), 0, stream,
                       x, skbuf, sk_t, ckbuf, ck_t, out0, tk);
}

// Round 9
// 351.690 us; speedup vs baseline: 2.6377x; 2.6377x over previous
//
// Round-9: sink-targeted polish. prep transpose -> 16B vectorized stores;
// mega1 (g1+batch sk/ck, proven r6/r8); final tk grid-strided.
// 7 dispatches: prep -> mega1 -> g2 -> g3 -> g4 -> task -> final.
#include <hip/hip_runtime.h>
#include <hip/hip_bf16.h>
#include <math.h>

#define BNEPS 1e-5f
#define BDIM_B 128
#define CDIM 512
#define SS 121
#define KK 9
#define MROWS (BDIM_B * SS)   // 15488

typedef unsigned short u16;
typedef __bf16 bf16x8 __attribute__((ext_vector_type(8)));
typedef float f32x4 __attribute__((ext_vector_type(4)));

__device__ __forceinline__ u16 f2bf(float f) {
    union { float f; unsigned int u; } v; v.f = f;
    unsigned int r = v.u + 0x7FFF + ((v.u >> 16) & 1);   // RNE
    return (u16)(r >> 16);
}
__device__ __forceinline__ float bf2f(u16 v) {
    union { unsigned int u; float f; } x; x.u = ((unsigned int)v) << 16; return x.f;
}

__device__ __forceinline__ void gld16(const u16* g, u16* l) {
    __builtin_amdgcn_global_load_lds(
        (const __attribute__((address_space(1))) void*)g,
        (__attribute__((address_space(3))) void*)l, 16, 0, 0);
}

// ---------------------------------------------------------------------------
// 128x128 BK=64 MFMA GEMM body (round-0 proven: ~50us @K=1024 grid 968).
// Shared memory passed in (AlsB/BlsB each 2*128*32 u16). Grid mapping = the
// proven 968-block XCD swizzle.
// MODE 1: relu -> bf16, p-major remap Y[(m%121)*128 + m/121][n]
// MODE 2: block rows all one p (= bx); relu, reduce 128 rows -> bf16
// ---------------------------------------------------------------------------
template<int MODE>
__device__ __forceinline__ void gemm128_body(
    const u16* __restrict__ A, const u16* __restrict__ Bw,
    const float* __restrict__ bias, const float* __restrict__ g,
    const float* __restrict__ bb, void* __restrict__ out,
    int Kd, int N, int bi, u16* AlsB, u16* BlsB)
{
    const int tid  = threadIdx.x;
    const int lane = tid & 63;
    const int w    = tid >> 6;
    const int wm   = w >> 1, wn = w & 1;

    int bx, by;
    {
        int i = bi;
        if (i < 960) {
            int xg = i & 7;
            int j  = i >> 3;
            bx = xg * 15 + (j >> 3);
            by = j & 7;
        } else { bx = 120; by = i - 960; }
    }
    const int bm = bx * 128;
    const int bn = by * 128;

    f32x4 acc[4][4] = {};

    const int subrow = tid >> 2;
    const int kq     = tid & 3;
    const int gchunk = kq ^ ((subrow >> 1) & 3);
    const u16* Ab = A  + (size_t)(bm + subrow) * Kd + gchunk * 8;
    const u16* Bb = Bw + (size_t)(bn + subrow) * Kd + gchunk * 8;
    u16* Al0  = AlsB + (w * 16) * 32;
    u16* Al1  = AlsB + (w * 16 + 64) * 32;
    u16* Bl0  = BlsB + (w * 16) * 32;
    u16* Bl1  = BlsB + (w * 16 + 64) * 32;
    u16* Al0b = AlsB + 4096 + (w * 16) * 32;
    u16* Al1b = AlsB + 4096 + (w * 16 + 64) * 32;
    u16* Bl0b = BlsB + 4096 + (w * 16) * 32;
    u16* Bl1b = BlsB + 4096 + (w * 16 + 64) * 32;

    const int fa_row = wm * 64 + (lane & 15);
    const int fb_row = wn * 64 + (lane & 15);
    const int kofs   = (((lane >> 4) ^ (((lane & 15) >> 1) & 3))) * 8;

    for (int k0 = 0; k0 < Kd; k0 += 64) {
        __syncthreads();
        gld16(Ab + k0,                      Al0);
        gld16(Ab + (size_t)64 * Kd + k0,    Al1);
        gld16(Bb + k0,                      Bl0);
        gld16(Bb + (size_t)64 * Kd + k0,    Bl1);
        gld16(Ab + k0 + 32,                 Al0b);
        gld16(Ab + (size_t)64 * Kd + k0 + 32, Al1b);
        gld16(Bb + k0 + 32,                 Bl0b);
        gld16(Bb + (size_t)64 * Kd + k0 + 32, Bl1b);
        __syncthreads();

        #pragma unroll
        for (int hb = 0; hb < 2; ++hb) {
            const u16* Ah = AlsB + hb * 4096;
            const u16* Bh = BlsB + hb * 4096;
            bf16x8 af[4], bfv[4];
            #pragma unroll
            for (int i = 0; i < 4; ++i)
                af[i] = *(const bf16x8*)&Ah[(fa_row + i * 16) * 32 + kofs];
            #pragma unroll
            for (int j = 0; j < 4; ++j)
                bfv[j] = *(const bf16x8*)&Bh[(fb_row + j * 16) * 32 + kofs];
            #pragma unroll
            for (int i = 0; i < 4; ++i)
                #pragma unroll
                for (int j = 0; j < 4; ++j)
                    acc[i][j] = __builtin_amdgcn_mfma_f32_16x16x32_bf16(af[i], bfv[j], acc[i][j], 0, 0, 0);
        }
    }

    const float inv = 1.0f / sqrtf(1.0f + BNEPS);

    if (MODE == 1) {
        u16* Y = (u16*)out;
        int dstrow[4][4];
        #pragma unroll
        for (int i = 0; i < 4; ++i) {
            int mb = bm + wm * 64 + i * 16 + (lane >> 4) * 4;
            #pragma unroll
            for (int r = 0; r < 4; ++r) {
                int m = mb + r;
                int b = m / 121, p = m - b * 121;
                dstrow[i][r] = p * 128 + b;
            }
        }
        #pragma unroll
        for (int j = 0; j < 4; ++j) {
            int n = bn + wn * 64 + j * 16 + (lane & 15);
            float sc = g[n] * inv, bo = bias[n], bv = bb[n];
            #pragma unroll
            for (int i = 0; i < 4; ++i)
                #pragma unroll
                for (int r = 0; r < 4; ++r) {
                    float v = (acc[i][j][r] + bo) * sc + bv;
                    v = fmaxf(v, 0.0f);
                    Y[(size_t)dstrow[i][r] * N + n] = f2bf(v);
                }
        }
    } else {
        float ps[4];
        #pragma unroll
        for (int j = 0; j < 4; ++j) {
            int n = bn + wn * 64 + j * 16 + (lane & 15);
            float sc = g[n] * inv, bo = bias[n], bv = bb[n];
            float s = 0.f;
            #pragma unroll
            for (int i = 0; i < 4; ++i)
                #pragma unroll
                for (int r = 0; r < 4; ++r) {
                    float v = (acc[i][j][r] + bo) * sc + bv;
                    s += fmaxf(v, 0.0f);
                }
            ps[j] = s;
        }
        __syncthreads();
        float* red = (float*)AlsB;
        #pragma unroll
        for (int j = 0; j < 4; ++j)
            red[(wm * 4 + (lane >> 4)) * 128 + wn * 64 + j * 16 + (lane & 15)] = ps[j];
        __syncthreads();
        if (tid < 128) {
            float s = 0.f;
            #pragma unroll
            for (int r = 0; r < 8; ++r) s += red[r * 128 + tid];
            ((u16*)out)[(size_t)bx * N + bn + tid] = f2bf(s);
        }
    }
}

template<int MODE>
__global__ __launch_bounds__(256)
void gemm_mfma(const u16* __restrict__ A, const u16* __restrict__ Bw,
               const float* __restrict__ bias, const float* __restrict__ g,
               const float* __restrict__ bb, void* __restrict__ out,
               int Kd, int N)
{
    __shared__ __align__(16) u16 shmem[4][128 * 32];
    gemm128_body<MODE>(A, Bw, bias, g, bb, out, Kd, N, blockIdx.x,
                       &shmem[0][0], &shmem[2][0]);
}

// ---------------------------------------------------------------------------
// barrier-free small GEMM (M=128), 32-col blocks (round-7 proven).
// MODE 3: relu; MODE 4: sigmoid. Y[m*N+n] bf16.
// ---------------------------------------------------------------------------
template<int MODE>
__global__ __launch_bounds__(256)
void gemm_small(const u16* __restrict__ A, const u16* __restrict__ Bw,
                const float* __restrict__ bias, const float* __restrict__ g,
                const float* __restrict__ bb, u16* __restrict__ Y,
                int Kd, int N)
{
    const int bn   = blockIdx.x * 32;
    const int tid  = threadIdx.x;
    const int lane = tid & 63;
    const int w    = tid >> 6;
    const int fr   = lane & 15;
    const int kq   = lane >> 4;
    const int r0   = w * 32;

    f32x4 acc[2][2] = {};
    const u16* a0p = A + (size_t)(r0 + fr) * Kd + kq * 8;
    const u16* a1p = a0p + (size_t)16 * Kd;
    const u16* b0p = Bw + (size_t)(bn + fr) * Kd + kq * 8;
    const u16* b1p = b0p + (size_t)16 * Kd;

    #pragma unroll 4
    for (int k0 = 0; k0 < Kd; k0 += 32) {
        bf16x8 a0 = *(const bf16x8*)(a0p + k0);
        bf16x8 a1 = *(const bf16x8*)(a1p + k0);
        bf16x8 b0 = *(const bf16x8*)(b0p + k0);
        bf16x8 b1 = *(const bf16x8*)(b1p + k0);
        acc[0][0] = __builtin_amdgcn_mfma_f32_16x16x32_bf16(a0, b0, acc[0][0], 0, 0, 0);
        acc[0][1] = __builtin_amdgcn_mfma_f32_16x16x32_bf16(a0, b1, acc[0][1], 0, 0, 0);
        acc[1][0] = __builtin_amdgcn_mfma_f32_16x16x32_bf16(a1, b0, acc[1][0], 0, 0, 0);
        acc[1][1] = __builtin_amdgcn_mfma_f32_16x16x32_bf16(a1, b1, acc[1][1], 0, 0, 0);
    }

    const float inv = 1.0f / sqrtf(1.0f + BNEPS);
    #pragma unroll
    for (int j = 0; j < 2; ++j) {
        int n = bn + j * 16 + (lane & 15);
        float sc = g[n] * inv, bo = bias[n], bv = bb[n];
        #pragma unroll
        for (int t = 0; t < 2; ++t)
            #pragma unroll
            for (int r = 0; r < 4; ++r) {
                int m = r0 + t * 16 + (lane >> 4) * 4 + r;
                float v = (acc[t][j][r] + bo) * sc + bv;
                if (MODE == 3) v = fmaxf(v, 0.0f);
                else           v = 1.f / (1.f + expf(-v));
                Y[(size_t)m * N + n] = f2bf(v);
            }
    }
}

// ---------------------------------------------------------------------------
// spatial kernel body (proven): 128-row MFMA GEMM vs wcb (16x512, L1-hot).
// ---------------------------------------------------------------------------
__device__ __forceinline__ void spatial_body(
    const u16* __restrict__ Arow, const u16* __restrict__ wcb,
    const float* __restrict__ b_conv, const float* __restrict__ g_sp,
    const float* __restrict__ b_sp, float* __restrict__ skb,
    bool task, int blk, float* __restrict__ skt)
{
    const float inv = 1.0f / sqrtf(1.0f + BNEPS);
    const int lane = threadIdx.x & 63;
    const int w    = threadIdx.x >> 6;
    const int fr   = lane & 15;
    const int kq   = lane >> 4;
    const int r0   = w * 32;

    f32x4 acc0 = {}, acc1 = {};
    const u16* a0p = Arow + (size_t)(r0 + fr) * 512 + kq * 8;
    const u16* a1p = a0p + (size_t)16 * 512;
    const u16* bp  = wcb + (size_t)fr * 512 + kq * 8;
    #pragma unroll
    for (int k0 = 0; k0 < 512; k0 += 32) {
        bf16x8 a0 = *(const bf16x8*)(a0p + k0);
        bf16x8 a1 = *(const bf16x8*)(a1p + k0);
        bf16x8 b  = *(const bf16x8*)(bp + k0);
        acc0 = __builtin_amdgcn_mfma_f32_16x16x32_bf16(a0, b, acc0, 0, 0, 0);
        acc1 = __builtin_amdgcn_mfma_f32_16x16x32_bf16(a1, b, acc1, 0, 0, 0);
    }

    int n = lane & 15;
    if (n < 9) {
        float bo = b_conv[n];
        #pragma unroll
        for (int t = 0; t < 2; ++t) {
            f32x4 a = t ? acc1 : acc0;
            #pragma unroll
            for (int r = 0; r < 4; ++r) {
                int mloc = r0 + t * 16 + (lane >> 4) * 4 + r;
                if (!task) {
                    int m = blk * 128 + mloc;
                    int p = m % 121;
                    float v = (a[r] + bo) * (g_sp[p] * inv) + b_sp[p];
                    skb[(size_t)m * 9 + n] = v;
                } else if (mloc < 121) {
                    float v = (a[r] + bo) * (g_sp[mloc] * inv) + b_sp[mloc];
                    skt[(size_t)mloc * 9 + n] = v;
                }
            }
        }
    }
}

// ---------------------------------------------------------------------------
// channel chain body (proven): DCT pool (2c/thread) -> fc1 -> fc2+sig+BN.
// ---------------------------------------------------------------------------
__device__ __forceinline__ void channel_body(
    const u16* __restrict__ src, const float* __restrict__ dctT,
    const float* __restrict__ fc1, const float* __restrict__ fc2,
    const float* __restrict__ g_ch, const float* __restrict__ b_ch,
    float* __restrict__ outp, float* yls, float* y2ls)
{
    const float inv = 1.0f / sqrtf(1.0f + BNEPS);

    {
        int c = threadIdx.x * 2;
        float s0 = 0.f, s1 = 0.f;
        for (int p = 0; p < SS; ++p) {
            unsigned v = *(const unsigned*)(src + (size_t)p * 512 + c);
            float2 d  = *(const float2*)(dctT + (size_t)p * 512 + c);
            s0 += bf2f((u16)(v & 0xFFFFu)) * d.x;
            s1 += bf2f((u16)(v >> 16)) * d.y;
        }
        yls[c] = s0; yls[c + 1] = s1;
    }
    __syncthreads();

    {
        int o = threadIdx.x >> 3, kp = threadIdx.x & 7;
        const float* w = fc1 + (size_t)o * 512;
        float s = 0.f;
        for (int k = kp * 4; k < 512; k += 32) {
            float4 wv = *(const float4*)(w + k);
            float4 av = *(const float4*)(yls + k);
            s += wv.x * av.x + wv.y * av.y + wv.z * av.z + wv.w * av.w;
        }
        s += __shfl_xor(s, 1);
        s += __shfl_xor(s, 2);
        s += __shfl_xor(s, 4);
        if (kp == 0) y2ls[o] = fmaxf(s, 0.f);
    }
    __syncthreads();

    for (int o = threadIdx.x; o < CDIM * KK; o += 256) {
        const float* w = fc2 + (size_t)o * 32;
        float s = 0.f;
        #pragma unroll
        for (int k = 0; k < 32; ++k) s += y2ls[k] * w[k];
        s = 1.f / (1.f + expf(-s));
        int c = o / KK;
        s = s * (g_ch[c] * inv) + b_ch[c];
        outp[o] = s;
    }
}

// ---------------------------------------------------------------------------
// mega1 (proven r6/r8): blocks [0,968) g1 GEMM; [968,1089) batch spatial;
// [1089,1217) batch channel. All depend only on prep.
// ---------------------------------------------------------------------------
__global__ __launch_bounds__(256)
void mega1(const u16* __restrict__ Xb, const u16* __restrict__ w1b,
           const float* __restrict__ up_b1, const float* __restrict__ up_g1,
           const float* __restrict__ up_bb1, u16* __restrict__ Y1,
           const u16* __restrict__ wcb, const float* __restrict__ b_conv,
           const float* __restrict__ g_sp, const float* __restrict__ b_sp,
           const float* __restrict__ dctT,
           const float* __restrict__ fc1, const float* __restrict__ fc2,
           const float* __restrict__ g_ch, const float* __restrict__ b_ch,
           float* __restrict__ skb, float* __restrict__ ckbuf)
{
    __shared__ __align__(16) u16 shmem[4][128 * 32];
    int bi = blockIdx.x;
    if (bi < 968) {
        gemm128_body<1>(Xb, w1b, up_b1, up_g1, up_bb1, (void*)Y1, 512, 1024, bi,
                        &shmem[0][0], &shmem[2][0]);
        return;
    }
    bi -= 968;
    if (bi < 121) {
        spatial_body(Xb + (size_t)bi * 128 * 512, wcb, b_conv, g_sp, b_sp,
                     skb, false, bi, nullptr);
        return;
    }
    bi -= 121;   // 0..127
    float* sm = (float*)&shmem[0][0];
    channel_body(Xb + (size_t)bi * 121 * 512, dctT, fc1, fc2, g_ch, b_ch,
                 ckbuf + (size_t)bi * CDIM * KK, sm, sm + 512);
}

// ---------------------------------------------------------------------------
// task combo (2 blocks, proven r5): task spatial -> skt, task channel -> ck_t
// ---------------------------------------------------------------------------
__global__ __launch_bounds__(256)
void task_combo(const u16* __restrict__ ts_pc, const u16* __restrict__ wcb,
                const float* __restrict__ b_conv, const float* __restrict__ g_sp,
                const float* __restrict__ b_sp, const float* __restrict__ dctT,
                const float* __restrict__ fc1, const float* __restrict__ fc2,
                const float* __restrict__ g_ch, const float* __restrict__ b_ch,
                float* __restrict__ skt, float* __restrict__ ck_t)
{
    __shared__ float sm[544];
    if (blockIdx.x == 0)
        spatial_body(ts_pc, wcb, b_conv, g_sp, b_sp, nullptr, true, 0, skt);
    else
        channel_body(ts_pc, dctT, fc1, fc2, g_ch, b_ch, ck_t, sm, sm + 512);
}

// ---------------------------------------------------------------------------
// prep combo: blocks [0,1024): x transpose -> Xb bf16, 16B vectorized stores
//   (8 channels packed per thread; same f2bf values, layout-only change).
// then: vectorized weight casts, dct transpose, w_conv pad.
// ---------------------------------------------------------------------------
#define W1N (1024 * 512)
#define W2N (1024 * 1024)
#define L1N (1024 * 1024)
#define L2N (512 * 1024)
#define VECN ((W1N + W2N + L1N + L2N) / 4)   // 786432 quads
#define DCTN (512 * 121)
#define WCN (16 * 512)
#define PREP_ELEM (VECN + DCTN + WCN)
#define PREP_BLKS (1024 + (PREP_ELEM + 255) / 256)
__global__ void prep_combo(const float* __restrict__ x, u16* __restrict__ Xb,
                           const float* __restrict__ w1, const float* __restrict__ w2,
                           const float* __restrict__ l1, const float* __restrict__ l2,
                           const float* __restrict__ dct, const float* __restrict__ w_conv,
                           u16* __restrict__ o1, u16* __restrict__ o2,
                           u16* __restrict__ o3, u16* __restrict__ o4,
                           float* __restrict__ dctT, u16* __restrict__ wcb)
{
    __shared__ float t[64 * 121];
    if (blockIdx.x < 1024) {
        int b = blockIdx.x >> 3, c0 = (blockIdx.x & 7) * 64;
        for (int idx = threadIdx.x; idx < 64 * 121; idx += 256) {
            int c = idx / 121, p = idx - c * 121;
            t[idx] = x[((size_t)b * 512 + c0 + c) * 121 + p];
        }
        __syncthreads();
        // 968 items: p(121) x cgroup(8); each packs 8 channels -> uint4 store
        for (int idx = threadIdx.x; idx < 121 * 8; idx += 256) {
            int p = idx >> 3, cg = (idx & 7) * 8;
            unsigned pk[4];
            #pragma unroll
            for (int j = 0; j < 4; ++j) {
                u16 lo = f2bf(t[(cg + 2 * j) * 121 + p]);
                u16 hi = f2bf(t[(cg + 2 * j + 1) * 121 + p]);
                pk[j] = (unsigned)lo | ((unsigned)hi << 16);
            }
            uint4 v; v.x = pk[0]; v.y = pk[1]; v.z = pk[2]; v.w = pk[3];
            *(uint4*)&Xb[((size_t)(b * 121 + p)) * 512 + c0 + cg] = v;
        }
        return;
    }
    int i = (blockIdx.x - 1024) * 256 + threadIdx.x;
    if (i < VECN) {
        int q = i;
        const float* s; u16* d;
        if (q < W1N / 4)                    { s = w1; d = o1; }
        else if (q < (W1N + W2N) / 4)       { s = w2; d = o2; q -= W1N / 4; }
        else if (q < (W1N + W2N + L1N) / 4) { s = l1; d = o3; q -= (W1N + W2N) / 4; }
        else                                { s = l2; d = o4; q -= (W1N + W2N + L1N) / 4; }
        float4 v = ((const float4*)s)[q];
        uint2 r;
        r.x = (unsigned)f2bf(v.x) | ((unsigned)f2bf(v.y) << 16);
        r.y = (unsigned)f2bf(v.z) | ((unsigned)f2bf(v.w) << 16);
        ((uint2*)d)[q] = r;
        return;
    }
    i -= VECN;
    if (i < DCTN) {
        int p = i >> 9, c = i & 511;
        dctT[i] = dct[(size_t)c * 121 + p];
        return;
    }
    i -= DCTN;
    if (i < WCN) {
        int n = i >> 9, c = i & 511;
        wcb[i] = (n < 9) ? f2bf(w_conv[(size_t)n * 512 + c]) : (u16)0;
    }
}

// ---------------------------------------------------------------------------
// final combo: blocks [0,1024) fused adapt; blocks [1024,1024+512) tk write
// (grid-strided — fewer near-idle blocks than one-shot).
// ---------------------------------------------------------------------------
#define TKN (CDIM * SS * KK)              // 557568
#define TK_BLKS 512
#define FIN_BLKS (1024 + TK_BLKS)
__global__ __launch_bounds__(256)
void final_combo(const float* __restrict__ x, const float* __restrict__ skb,
                 const float* __restrict__ sk_t, const float* __restrict__ ckbuf,
                 const float* __restrict__ ck_t, float* __restrict__ out0,
                 float* __restrict__ tk)
{
    __shared__ float PS[SS * KK];
    __shared__ float CS[64 * KK];
    __shared__ float XT[64 * SS];

    if (blockIdx.x >= 1024) {
        int base = (blockIdx.x - 1024) * 256 + threadIdx.x;
        for (int idx = base; idx < TKN; idx += TK_BLKS * 256) {
            int k9 = idx % KK;
            int pc = idx / KK;
            int p = pc % SS, c = pc / SS;
            tk[idx] = sk_t[p * KK + k9] * ck_t[c * KK + k9];
        }
        return;
    }

    const int tid = threadIdx.x;
    const int b = blockIdx.x >> 3, c0 = (blockIdx.x & 7) * 64;

    const float* sp = skb + (size_t)b * SS * KK;
    for (int i = tid; i < SS * KK; i += 256) PS[i] = sp[i] * sk_t[i];
    const float* cp = ckbuf + ((size_t)b * CDIM + c0) * KK;
    const float* tp = ck_t + (size_t)c0 * KK;
    for (int i = tid; i < (64 * KK) / 4; i += 256) {
        float4 a = ((const float4*)cp)[i];
        float4 bq = ((const float4*)tp)[i];
        float4 r; r.x = a.x * bq.x; r.y = a.y * bq.y; r.z = a.z * bq.z; r.w = a.w * bq.w;
        ((float4*)CS)[i] = r;
    }
    const float* xp = x + ((size_t)b * CDIM + c0) * SS;
    for (int i = tid; i < (64 * SS) / 4; i += 256)
        ((float4*)XT)[i] = ((const float4*)xp)[i];
    __syncthreads();

    float* op = out0 + ((size_t)b * CDIM + c0) * SS;
    for (int ci = tid; ci < (64 * SS) / 4; ci += 256) {
        float4 o;
        #pragma unroll
        for (int r = 0; r < 4; ++r) {
            int i = ci * 4 + r;
            int c = i / SS, p = i - c * SS;
            int h = p / 11, w = p - h * 11;
            const float* xc = XT + c * SS;
            const float* ps = PS + p * KK;
            const float* cs = CS + c * KK;
            float acc = 0.f;
            #pragma unroll
            for (int di = 0; di < 3; ++di) {
                int hh = h + di - 1;
                bool hv = (unsigned)hh < 11u;
                #pragma unroll
                for (int dj = 0; dj < 3; ++dj) {
                    int ww = w + dj - 1;
                    int k = di * 3 + dj;
                    float xv = (hv && (unsigned)ww < 11u) ? xc[hh * 11 + ww] : 0.f;
                    acc += xv * ps[k] * cs[k];
                }
            }
            ((float*)&o)[r] = acc * (1.0f / 9.0f) + xc[p];
        }
        ((float4*)op)[ci] = o;
    }
}

extern "C" void kernel_launch(void* const* d_in, const int* in_sizes, int n_in,
                              void* d_out, int out_size, void* d_ws, size_t ws_size,
                              hipStream_t stream)
{
    const float* x      = (const float*)d_in[0];
    const float* dct_w  = (const float*)d_in[1];
    const float* w_conv = (const float*)d_in[2];
    const float* b_conv = (const float*)d_in[3];
    const float* g_sp   = (const float*)d_in[4];
    const float* b_sp   = (const float*)d_in[5];
    const float* g_ch   = (const float*)d_in[6];
    const float* b_ch   = (const float*)d_in[7];
    const float* fc1    = (const float*)d_in[8];
    const float* fc2    = (const float*)d_in[9];
    const float* up_w1  = (const float*)d_in[10];
    const float* up_b1  = (const float*)d_in[11];
    const float* up_g1  = (const float*)d_in[12];
    const float* up_bb1 = (const float*)d_in[13];
    const float* up_w2  = (const float*)d_in[14];
    const float* up_b2  = (const float*)d_in[15];
    const float* up_g2  = (const float*)d_in[16];
    const float* up_bb2 = (const float*)d_in[17];
    const float* lo_w1  = (const float*)d_in[18];
    const float* lo_b1  = (const float*)d_in[19];
    const float* lo_g1  = (const float*)d_in[20];
    const float* lo_bb1 = (const float*)d_in[21];
    const float* lo_w2  = (const float*)d_in[22];
    const float* lo_b2  = (const float*)d_in[23];
    const float* lo_g2  = (const float*)d_in[24];
    const float* lo_bb2 = (const float*)d_in[25];

    float* out0 = (float*)d_out;                       // (B,C,11,11)
    float* tk   = out0 + (size_t)BDIM_B * CDIM * SS;   // (1,C,11,11,3,3)

    // workspace layout (bytes, 64B-aligned chunks)
    char* ws = (char*)d_ws;
    size_t off = 0;
    auto alloc = [&](size_t bytes) { void* p = ws + off; off += (bytes + 63) & ~(size_t)63; return p; };
    u16*   Xb      = (u16*)alloc((size_t)MROWS * 512 * 2);
    u16*   Y1      = (u16*)alloc((size_t)MROWS * 1024 * 2);
    u16*   w1b     = (u16*)alloc((size_t)W1N * 2);
    u16*   w2b     = (u16*)alloc((size_t)W2N * 2);
    u16*   lw1b    = (u16*)alloc((size_t)L1N * 2);
    u16*   lw2b    = (u16*)alloc((size_t)L2N * 2);
    u16*   asum_b  = (u16*)alloc((size_t)128 * 1024 * 2);   // rows 121..127 unwritten
    u16*   a3b     = (u16*)alloc((size_t)128 * 1024 * 2);
    u16*   ts_pc   = (u16*)alloc((size_t)128 * 512 * 2);    // task_s (p,c) bf16
    float* dctT    = (float*)alloc((size_t)SS * 512 * 4);
    u16*   wcb     = (u16*)alloc((size_t)WCN * 2);          // w_conv bf16 16x512 (pad)
    float* ckbuf   = (float*)alloc((size_t)BDIM_B * CDIM * KK * 4);
    float* skbuf   = (float*)alloc((size_t)BDIM_B * SS * KK * 4);
    float* ck_t    = (float*)alloc((size_t)CDIM * KK * 4);
    float* sk_t    = (float*)alloc((size_t)SS * KK * 4);

    // --- 1. prep: x transpose (16B stores) + weight casts + dct transpose ---
    hipLaunchKernelGGL(prep_combo, dim3(PREP_BLKS), dim3(256), 0, stream,
                       x, Xb, up_w1, up_w2, lo_w1, lo_w2, dct_w, w_conv,
                       w1b, w2b, lw1b, lw2b, dctT, wcb);

    // --- 2. mega1: g1 GEMM + batch spatial + batch channel (1217 blocks) ---
    hipLaunchKernelGGL(mega1, dim3(968 + 121 + 128), dim3(256), 0, stream,
                       Xb, w1b, up_b1, up_g1, up_bb1, Y1,
                       wcb, b_conv, g_sp, b_sp,
                       dctT, fc1, fc2, g_ch, b_ch,
                       skbuf, ckbuf);

    // --- 3. g2: batch-reduced GEMM (proven BK=64 structure, grid 968) ---
    hipLaunchKernelGGL((gemm_mfma<2>), dim3(968), dim3(256), 0, stream,
                       Y1, w2b, up_b2, up_g2, up_bb2, (void*)asum_b, 1024, 1024);

    // --- 4/5. lo path: barrier-free 32-col GEMMs (32 + 16 blocks) ---
    hipLaunchKernelGGL((gemm_small<3>), dim3(32), dim3(256), 0, stream,
                       asum_b, lw1b, lo_b1, lo_g1, lo_bb1, a3b, 1024, 1024);
    hipLaunchKernelGGL((gemm_small<4>), dim3(16), dim3(256), 0, stream,
                       a3b, lw2b, lo_b2, lo_g2, lo_bb2, ts_pc, 1024, 512);

    // --- 6. task spatial + channel (2 blocks) ---
    hipLaunchKernelGGL(task_combo, dim3(2), dim3(256), 0, stream,
                       ts_pc, wcb, b_conv, g_sp, b_sp,
                       dctT, fc1, fc2, g_ch, b_ch, sk_t, ck_t);

    // --- 7. final fused + task-kernel write ---
    hipLaunchKernelGGL(final_combo, dim3(FIN_BLKS), dim3(256), 0, stream,
                       x, skbuf, sk_t, ckbuf, ck_t, out0, tk);
}

// Round 10
// 312.747 us; speedup vs baseline: 2.9662x; 1.1245x over previous
//
// Round-10: ring-3 counted-vmcnt K-pipeline for g1/g2 (T4, no in-loop drain),
// on the PROVEN 128^2 layout (fragments/swizzle/epilogues/VGPR unchanged).
// Everything else = round-7 config + round-9 prep/tk improvements.
#include <hip/hip_runtime.h>
#include <hip/hip_bf16.h>
#include <math.h>

#define BNEPS 1e-5f
#define BDIM_B 128
#define CDIM 512
#define SS 121
#define KK 9
#define MROWS (BDIM_B * SS)   // 15488

typedef unsigned short u16;
typedef __bf16 bf16x8 __attribute__((ext_vector_type(8)));
typedef float f32x4 __attribute__((ext_vector_type(4)));

__device__ __forceinline__ u16 f2bf(float f) {
    union { float f; unsigned int u; } v; v.f = f;
    unsigned int r = v.u + 0x7FFF + ((v.u >> 16) & 1);   // RNE
    return (u16)(r >> 16);
}
__device__ __forceinline__ float bf2f(u16 v) {
    union { unsigned int u; float f; } x; x.u = ((unsigned int)v) << 16; return x.f;
}

__device__ __forceinline__ void gld16(const u16* g, u16* l) {
    __builtin_amdgcn_global_load_lds(
        (const __attribute__((address_space(1))) void*)g,
        (__attribute__((address_space(3))) void*)l, 16, 0, 0);
}

__device__ __forceinline__ void wgbar() {
    asm volatile("" ::: "memory");
    __builtin_amdgcn_s_barrier();
    asm volatile("" ::: "memory");
}

// ---------------------------------------------------------------------------
// gemm_ring: 128x128 tile, BK=32, 3-slot LDS ring, counted vmcnt (never 0
// in the main loop). Fragment layout / source+read XOR swizzle / grid-968
// XCD mapping / epilogues are the PROVEN round-0 structure verbatim.
// Per tile t: ds_read frags(slot t%3) -> lgkmcnt(0) -> barrier ->
//   STAGE(t+3 -> slot t%3) -> 16 MFMA -> vmcnt(8) -> barrier.
// Invariant entering tile t: tile t landed block-wide; t+1,t+2 in flight.
// Epilogue: vmcnt(4) at t=NT-3, vmcnt(0) at t=NT-2.
// K-accumulation order identical to BK=64 half0/half1 -> bitwise-same output.
// MODE 1: relu -> bf16, p-major remap Y[(m%121)*128 + m/121][n]
// MODE 2: block rows all one p (= bx); relu, reduce 128 rows -> bf16
// ---------------------------------------------------------------------------
template<int MODE>
__global__ __launch_bounds__(256)
void gemm_ring(const u16* __restrict__ A, const u16* __restrict__ Bw,
               const float* __restrict__ bias, const float* __restrict__ g,
               const float* __restrict__ bb, void* __restrict__ out,
               int Kd, int N)
{
    __shared__ __align__(16) u16 As[3][128 * 32];
    __shared__ __align__(16) u16 Bs[3][128 * 32];

    const int tid  = threadIdx.x;
    const int lane = tid & 63;
    const int w    = tid >> 6;
    const int wm   = w >> 1, wn = w & 1;

    int bx, by;
    {
        int i = blockIdx.x;
        if (i < 960) {
            int xg = i & 7;
            int j  = i >> 3;
            bx = xg * 15 + (j >> 3);
            by = j & 7;
        } else { bx = 120; by = i - 960; }
    }
    const int bm = bx * 128;
    const int bn = by * 128;

    f32x4 acc[4][4] = {};

    const int subrow = tid >> 2;
    const int kq     = tid & 3;
    const int gchunk = kq ^ ((subrow >> 1) & 3);
    const u16* Ab = A  + (size_t)(bm + subrow) * Kd + gchunk * 8;
    const u16* Bb = Bw + (size_t)(bn + subrow) * Kd + gchunk * 8;

    const int fa_row = wm * 64 + (lane & 15);
    const int fb_row = wn * 64 + (lane & 15);
    const int kofs   = (((lane >> 4) ^ (((lane & 15) >> 1) & 3))) * 8;

    const int NT = Kd >> 5;   // BK=32 tiles (16 for K=512, 32 for K=1024)

#define STG(S_, T_) do { \
    gld16(Ab + (size_t)(T_) * 32,                 &As[S_][(w * 16) * 32]); \
    gld16(Ab + (size_t)64 * Kd + (size_t)(T_) * 32, &As[S_][(w * 16 + 64) * 32]); \
    gld16(Bb + (size_t)(T_) * 32,                 &Bs[S_][(w * 16) * 32]); \
    gld16(Bb + (size_t)64 * Kd + (size_t)(T_) * 32, &Bs[S_][(w * 16 + 64) * 32]); \
    asm volatile("" ::: "memory"); \
} while (0)

    // prologue: stage tiles 0,1,2 (12 loads); wait own tile-0 (vmcnt<=8);
    // barrier makes tile-0 landed block-wide.
    STG(0, 0);
    STG(1, 1);
    STG(2, 2);
    asm volatile("s_waitcnt vmcnt(8)" ::: "memory");
    wgbar();

    int sl = 0;
    for (int t = 0; t < NT; ++t) {
        bf16x8 af[4], bv[4];
        #pragma unroll
        for (int i = 0; i < 4; ++i)
            af[i] = *(const bf16x8*)&As[sl][(fa_row + i * 16) * 32 + kofs];
        #pragma unroll
        for (int j = 0; j < 4; ++j)
            bv[j] = *(const bf16x8*)&Bs[sl][(fb_row + j * 16) * 32 + kofs];
        asm volatile("s_waitcnt lgkmcnt(0)" ::: "memory");   // frags in regs
        wgbar();                                             // block-wide: slot free
        if (t + 3 < NT) STG(sl, t + 3);                      // refill freed slot
        __builtin_amdgcn_s_setprio(1);
        #pragma unroll
        for (int i = 0; i < 4; ++i)
            #pragma unroll
            for (int j = 0; j < 4; ++j)
                acc[i][j] = __builtin_amdgcn_mfma_f32_16x16x32_bf16(af[i], bv[j], acc[i][j], 0, 0, 0);
        __builtin_amdgcn_s_setprio(0);
        if (t < NT - 3)       { asm volatile("s_waitcnt vmcnt(8)" ::: "memory"); }
        else if (t == NT - 3) { asm volatile("s_waitcnt vmcnt(4)" ::: "memory"); }
        else if (t == NT - 2) { asm volatile("s_waitcnt vmcnt(0)" ::: "memory"); }
        if (t < NT - 1) wgbar();                             // next tile landed block-wide
        sl = (sl == 2) ? 0 : sl + 1;
    }
#undef STG

    const float inv = 1.0f / sqrtf(1.0f + BNEPS);

    if (MODE == 1) {
        u16* Y = (u16*)out;
        int dstrow[4][4];
        #pragma unroll
        for (int i = 0; i < 4; ++i) {
            int mb = bm + wm * 64 + i * 16 + (lane >> 4) * 4;
            #pragma unroll
            for (int r = 0; r < 4; ++r) {
                int m = mb + r;
                int b = m / 121, p = m - b * 121;
                dstrow[i][r] = p * 128 + b;
            }
        }
        #pragma unroll
        for (int j = 0; j < 4; ++j) {
            int n = bn + wn * 64 + j * 16 + (lane & 15);
            float sc = g[n] * inv, bo = bias[n], bv2 = bb[n];
            #pragma unroll
            for (int i = 0; i < 4; ++i)
                #pragma unroll
                for (int r = 0; r < 4; ++r) {
                    float v = (acc[i][j][r] + bo) * sc + bv2;
                    v = fmaxf(v, 0.0f);
                    Y[(size_t)dstrow[i][r] * N + n] = f2bf(v);
                }
        }
    } else {
        float ps[4];
        #pragma unroll
        for (int j = 0; j < 4; ++j) {
            int n = bn + wn * 64 + j * 16 + (lane & 15);
            float sc = g[n] * inv, bo = bias[n], bv2 = bb[n];
            float s = 0.f;
            #pragma unroll
            for (int i = 0; i < 4; ++i)
                #pragma unroll
                for (int r = 0; r < 4; ++r) {
                    float v = (acc[i][j][r] + bo) * sc + bv2;
                    s += fmaxf(v, 0.0f);
                }
            ps[j] = s;
        }
        __syncthreads();
        float* red = (float*)&As[0][0];      // 4KB scratch, slot0 free now
        #pragma unroll
        for (int j = 0; j < 4; ++j)
            red[(wm * 4 + (lane >> 4)) * 128 + wn * 64 + j * 16 + (lane & 15)] = ps[j];
        __syncthreads();
        if (tid < 128) {
            float s = 0.f;
            #pragma unroll
            for (int r = 0; r < 8; ++r) s += red[r * 128 + tid];
            ((u16*)out)[(size_t)bx * N + bn + tid] = f2bf(s);
        }
    }
}

// ---------------------------------------------------------------------------
// barrier-free small GEMM (M=128), 32-col blocks (round-7 proven).
// MODE 3: relu; MODE 4: sigmoid. Y[m*N+n] bf16.
// ---------------------------------------------------------------------------
template<int MODE>
__global__ __launch_bounds__(256)
void gemm_small(const u16* __restrict__ A, const u16* __restrict__ Bw,
                const float* __restrict__ bias, const float* __restrict__ g,
                const float* __restrict__ bb, u16* __restrict__ Y,
                int Kd, int N)
{
    const int bn   = blockIdx.x * 32;
    const int tid  = threadIdx.x;
    const int lane = tid & 63;
    const int w    = tid >> 6;
    const int fr   = lane & 15;
    const int kq   = lane >> 4;
    const int r0   = w * 32;

    f32x4 acc[2][2] = {};
    const u16* a0p = A + (size_t)(r0 + fr) * Kd + kq * 8;
    const u16* a1p = a0p + (size_t)16 * Kd;
    const u16* b0p = Bw + (size_t)(bn + fr) * Kd + kq * 8;
    const u16* b1p = b0p + (size_t)16 * Kd;

    #pragma unroll 4
    for (int k0 = 0; k0 < Kd; k0 += 32) {
        bf16x8 a0 = *(const bf16x8*)(a0p + k0);
        bf16x8 a1 = *(const bf16x8*)(a1p + k0);
        bf16x8 b0 = *(const bf16x8*)(b0p + k0);
        bf16x8 b1 = *(const bf16x8*)(b1p + k0);
        acc[0][0] = __builtin_amdgcn_mfma_f32_16x16x32_bf16(a0, b0, acc[0][0], 0, 0, 0);
        acc[0][1] = __builtin_amdgcn_mfma_f32_16x16x32_bf16(a0, b1, acc[0][1], 0, 0, 0);
        acc[1][0] = __builtin_amdgcn_mfma_f32_16x16x32_bf16(a1, b0, acc[1][0], 0, 0, 0);
        acc[1][1] = __builtin_amdgcn_mfma_f32_16x16x32_bf16(a1, b1, acc[1][1], 0, 0, 0);
    }

    const float inv = 1.0f / sqrtf(1.0f + BNEPS);
    #pragma unroll
    for (int j = 0; j < 2; ++j) {
        int n = bn + j * 16 + (lane & 15);
        float sc = g[n] * inv, bo = bias[n], bv = bb[n];
        #pragma unroll
        for (int t = 0; t < 2; ++t)
            #pragma unroll
            for (int r = 0; r < 4; ++r) {
                int m = r0 + t * 16 + (lane >> 4) * 4 + r;
                float v = (acc[t][j][r] + bo) * sc + bv;
                if (MODE == 3) v = fmaxf(v, 0.0f);
                else           v = 1.f / (1.f + expf(-v));
                Y[(size_t)m * N + n] = f2bf(v);
            }
    }
}

// ---------------------------------------------------------------------------
// spatial kernel body (proven): 128-row MFMA GEMM vs wcb (16x512, L1-hot).
// ---------------------------------------------------------------------------
__device__ __forceinline__ void spatial_body(
    const u16* __restrict__ Arow, const u16* __restrict__ wcb,
    const float* __restrict__ b_conv, const float* __restrict__ g_sp,
    const float* __restrict__ b_sp, float* __restrict__ skb,
    bool task, int blk, float* __restrict__ skt)
{
    const float inv = 1.0f / sqrtf(1.0f + BNEPS);
    const int lane = threadIdx.x & 63;
    const int w    = threadIdx.x >> 6;
    const int fr   = lane & 15;
    const int kq   = lane >> 4;
    const int r0   = w * 32;

    f32x4 acc0 = {}, acc1 = {};
    const u16* a0p = Arow + (size_t)(r0 + fr) * 512 + kq * 8;
    const u16* a1p = a0p + (size_t)16 * 512;
    const u16* bp  = wcb + (size_t)fr * 512 + kq * 8;
    #pragma unroll
    for (int k0 = 0; k0 < 512; k0 += 32) {
        bf16x8 a0 = *(const bf16x8*)(a0p + k0);
        bf16x8 a1 = *(const bf16x8*)(a1p + k0);
        bf16x8 b  = *(const bf16x8*)(bp + k0);
        acc0 = __builtin_amdgcn_mfma_f32_16x16x32_bf16(a0, b, acc0, 0, 0, 0);
        acc1 = __builtin_amdgcn_mfma_f32_16x16x32_bf16(a1, b, acc1, 0, 0, 0);
    }

    int n = lane & 15;
    if (n < 9) {
        float bo = b_conv[n];
        #pragma unroll
        for (int t = 0; t < 2; ++t) {
            f32x4 a = t ? acc1 : acc0;
            #pragma unroll
            for (int r = 0; r < 4; ++r) {
                int mloc = r0 + t * 16 + (lane >> 4) * 4 + r;
                if (!task) {
                    int m = blk * 128 + mloc;
                    int p = m % 121;
                    float v = (a[r] + bo) * (g_sp[p] * inv) + b_sp[p];
                    skb[(size_t)m * 9 + n] = v;
                } else if (mloc < 121) {
                    float v = (a[r] + bo) * (g_sp[mloc] * inv) + b_sp[mloc];
                    skt[(size_t)mloc * 9 + n] = v;
                }
            }
        }
    }
}

// ---------------------------------------------------------------------------
// channel chain body (proven): DCT pool (2c/thread) -> fc1 -> fc2+sig+BN.
// ---------------------------------------------------------------------------
__device__ __forceinline__ void channel_body(
    const u16* __restrict__ src, const float* __restrict__ dctT,
    const float* __restrict__ fc1, const float* __restrict__ fc2,
    const float* __restrict__ g_ch, const float* __restrict__ b_ch,
    float* __restrict__ outp, float* yls, float* y2ls)
{
    const float inv = 1.0f / sqrtf(1.0f + BNEPS);

    {
        int c = threadIdx.x * 2;
        float s0 = 0.f, s1 = 0.f;
        for (int p = 0; p < SS; ++p) {
            unsigned v = *(const unsigned*)(src + (size_t)p * 512 + c);
            float2 d  = *(const float2*)(dctT + (size_t)p * 512 + c);
            s0 += bf2f((u16)(v & 0xFFFFu)) * d.x;
            s1 += bf2f((u16)(v >> 16)) * d.y;
        }
        yls[c] = s0; yls[c + 1] = s1;
    }
    __syncthreads();

    {
        int o = threadIdx.x >> 3, kp = threadIdx.x & 7;
        const float* w = fc1 + (size_t)o * 512;
        float s = 0.f;
        for (int k = kp * 4; k < 512; k += 32) {
            float4 wv = *(const float4*)(w + k);
            float4 av = *(const float4*)(yls + k);
            s += wv.x * av.x + wv.y * av.y + wv.z * av.z + wv.w * av.w;
        }
        s += __shfl_xor(s, 1);
        s += __shfl_xor(s, 2);
        s += __shfl_xor(s, 4);
        if (kp == 0) y2ls[o] = fmaxf(s, 0.f);
    }
    __syncthreads();

    for (int o = threadIdx.x; o < CDIM * KK; o += 256) {
        const float* w = fc2 + (size_t)o * 32;
        float s = 0.f;
        #pragma unroll
        for (int k = 0; k < 32; ++k) s += y2ls[k] * w[k];
        s = 1.f / (1.f + expf(-s));
        int c = o / KK;
        s = s * (g_ch[c] * inv) + b_ch[c];
        outp[o] = s;
    }
}

// ---------------------------------------------------------------------------
// spatial+channel, one 251-block dispatch (round-5/7 proven).
// ---------------------------------------------------------------------------
__global__ __launch_bounds__(256)
void spatial_ck_combo(const u16* __restrict__ Xb, const u16* __restrict__ Xt,
                      const u16* __restrict__ wcb, const float* __restrict__ b_conv,
                      const float* __restrict__ g_sp, const float* __restrict__ b_sp,
                      const float* __restrict__ dctT,
                      const float* __restrict__ fc1, const float* __restrict__ fc2,
                      const float* __restrict__ g_ch, const float* __restrict__ b_ch,
                      float* __restrict__ skb, float* __restrict__ skt,
                      float* __restrict__ ckbuf, float* __restrict__ ck_t)
{
    __shared__ float sm[544];
    if (blockIdx.x < 122) {
        const bool task = (blockIdx.x == 121);
        spatial_body(task ? Xt : Xb + (size_t)blockIdx.x * 128 * 512,
                     wcb, b_conv, g_sp, b_sp, skb, task, blockIdx.x, skt);
        return;
    }
    const int g = blockIdx.x - 122;                    // 0..128
    const u16* src = (g < 128) ? Xb + (size_t)g * 121 * 512 : Xt;
    channel_body(src, dctT, fc1, fc2, g_ch, b_ch,
                 (g < 128) ? ckbuf + (size_t)g * CDIM * KK : ck_t, sm, sm + 512);
}

// ---------------------------------------------------------------------------
// prep combo (round-9 proven): x transpose with 16B vectorized stores +
// vectorized weight casts + dct transpose + w_conv pad.
// ---------------------------------------------------------------------------
#define W1N (1024 * 512)
#define W2N (1024 * 1024)
#define L1N (1024 * 1024)
#define L2N (512 * 1024)
#define VECN ((W1N + W2N + L1N + L2N) / 4)   // 786432 quads
#define DCTN (512 * 121)
#define WCN (16 * 512)
#define PREP_ELEM (VECN + DCTN + WCN)
#define PREP_BLKS (1024 + (PREP_ELEM + 255) / 256)
__global__ void prep_combo(const float* __restrict__ x, u16* __restrict__ Xb,
                           const float* __restrict__ w1, const float* __restrict__ w2,
                           const float* __restrict__ l1, const float* __restrict__ l2,
                           const float* __restrict__ dct, const float* __restrict__ w_conv,
                           u16* __restrict__ o1, u16* __restrict__ o2,
                           u16* __restrict__ o3, u16* __restrict__ o4,
                           float* __restrict__ dctT, u16* __restrict__ wcb)
{
    __shared__ float t[64 * 121];
    if (blockIdx.x < 1024) {
        int b = blockIdx.x >> 3, c0 = (blockIdx.x & 7) * 64;
        for (int idx = threadIdx.x; idx < 64 * 121; idx += 256) {
            int c = idx / 121, p = idx - c * 121;
            t[idx] = x[((size_t)b * 512 + c0 + c) * 121 + p];
        }
        __syncthreads();
        for (int idx = threadIdx.x; idx < 121 * 8; idx += 256) {
            int p = idx >> 3, cg = (idx & 7) * 8;
            unsigned pk[4];
            #pragma unroll
            for (int j = 0; j < 4; ++j) {
                u16 lo = f2bf(t[(cg + 2 * j) * 121 + p]);
                u16 hi = f2bf(t[(cg + 2 * j + 1) * 121 + p]);
                pk[j] = (unsigned)lo | ((unsigned)hi << 16);
            }
            uint4 v; v.x = pk[0]; v.y = pk[1]; v.z = pk[2]; v.w = pk[3];
            *(uint4*)&Xb[((size_t)(b * 121 + p)) * 512 + c0 + cg] = v;
        }
        return;
    }
    int i = (blockIdx.x - 1024) * 256 + threadIdx.x;
    if (i < VECN) {
        int q = i;
        const float* s; u16* d;
        if (q < W1N / 4)                    { s = w1; d = o1; }
        else if (q < (W1N + W2N) / 4)       { s = w2; d = o2; q -= W1N / 4; }
        else if (q < (W1N + W2N + L1N) / 4) { s = l1; d = o3; q -= (W1N + W2N) / 4; }
        else                                { s = l2; d = o4; q -= (W1N + W2N + L1N) / 4; }
        float4 v = ((const float4*)s)[q];
        uint2 r;
        r.x = (unsigned)f2bf(v.x) | ((unsigned)f2bf(v.y) << 16);
        r.y = (unsigned)f2bf(v.z) | ((unsigned)f2bf(v.w) << 16);
        ((uint2*)d)[q] = r;
        return;
    }
    i -= VECN;
    if (i < DCTN) {
        int p = i >> 9, c = i & 511;
        dctT[i] = dct[(size_t)c * 121 + p];
        return;
    }
    i -= DCTN;
    if (i < WCN) {
        int n = i >> 9, c = i & 511;
        wcb[i] = (n < 9) ? f2bf(w_conv[(size_t)n * 512 + c]) : (u16)0;
    }
}

// ---------------------------------------------------------------------------
// final combo (round-9 proven): fused adapt + grid-strided tk write.
// ---------------------------------------------------------------------------
#define TKN (CDIM * SS * KK)              // 557568
#define TK_BLKS 512
#define FIN_BLKS (1024 + TK_BLKS)
__global__ __launch_bounds__(256)
void final_combo(const float* __restrict__ x, const float* __restrict__ skb,
                 const float* __restrict__ sk_t, const float* __restrict__ ckbuf,
                 const float* __restrict__ ck_t, float* __restrict__ out0,
                 float* __restrict__ tk)
{
    __shared__ float PS[SS * KK];
    __shared__ float CS[64 * KK];
    __shared__ float XT[64 * SS];

    if (blockIdx.x >= 1024) {
        int base = (blockIdx.x - 1024) * 256 + threadIdx.x;
        for (int idx = base; idx < TKN; idx += TK_BLKS * 256) {
            int k9 = idx % KK;
            int pc = idx / KK;
            int p = pc % SS, c = pc / SS;
            tk[idx] = sk_t[p * KK + k9] * ck_t[c * KK + k9];
        }
        return;
    }

    const int tid = threadIdx.x;
    const int b = blockIdx.x >> 3, c0 = (blockIdx.x & 7) * 64;

    const float* sp = skb + (size_t)b * SS * KK;
    for (int i = tid; i < SS * KK; i += 256) PS[i] = sp[i] * sk_t[i];
    const float* cp = ckbuf + ((size_t)b * CDIM + c0) * KK;
    const float* tp = ck_t + (size_t)c0 * KK;
    for (int i = tid; i < (64 * KK) / 4; i += 256) {
        float4 a = ((const float4*)cp)[i];
        float4 bq = ((const float4*)tp)[i];
        float4 r; r.x = a.x * bq.x; r.y = a.y * bq.y; r.z = a.z * bq.z; r.w = a.w * bq.w;
        ((float4*)CS)[i] = r;
    }
    const float* xp = x + ((size_t)b * CDIM + c0) * SS;
    for (int i = tid; i < (64 * SS) / 4; i += 256)
        ((float4*)XT)[i] = ((const float4*)xp)[i];
    __syncthreads();

    float* op = out0 + ((size_t)b * CDIM + c0) * SS;
    for (int ci = tid; ci < (64 * SS) / 4; ci += 256) {
        float4 o;
        #pragma unroll
        for (int r = 0; r < 4; ++r) {
            int i = ci * 4 + r;
            int c = i / SS, p = i - c * SS;
            int h = p / 11, w = p - h * 11;
            const float* xc = XT + c * SS;
            const float* ps = PS + p * KK;
            const float* cs = CS + c * KK;
            float acc = 0.f;
            #pragma unroll
            for (int di = 0; di < 3; ++di) {
                int hh = h + di - 1;
                bool hv = (unsigned)hh < 11u;
                #pragma unroll
                for (int dj = 0; dj < 3; ++dj) {
                    int ww = w + dj - 1;
                    int k = di * 3 + dj;
                    float xv = (hv && (unsigned)ww < 11u) ? xc[hh * 11 + ww] : 0.f;
                    acc += xv * ps[k] * cs[k];
                }
            }
            ((float*)&o)[r] = acc * (1.0f / 9.0f) + xc[p];
        }
        ((float4*)op)[ci] = o;
    }
}

extern "C" void kernel_launch(void* const* d_in, const int* in_sizes, int n_in,
                              void* d_out, int out_size, void* d_ws, size_t ws_size,
                              hipStream_t stream)
{
    const float* x      = (const float*)d_in[0];
    const float* dct_w  = (const float*)d_in[1];
    const float* w_conv = (const float*)d_in[2];
    const float* b_conv = (const float*)d_in[3];
    const float* g_sp   = (const float*)d_in[4];
    const float* b_sp   = (const float*)d_in[5];
    const float* g_ch   = (const float*)d_in[6];
    const float* b_ch   = (const float*)d_in[7];
    const float* fc1    = (const float*)d_in[8];
    const float* fc2    = (const float*)d_in[9];
    const float* up_w1  = (const float*)d_in[10];
    const float* up_b1  = (const float*)d_in[11];
    const float* up_g1  = (const float*)d_in[12];
    const float* up_bb1 = (const float*)d_in[13];
    const float* up_w2  = (const float*)d_in[14];
    const float* up_b2  = (const float*)d_in[15];
    const float* up_g2  = (const float*)d_in[16];
    const float* up_bb2 = (const float*)d_in[17];
    const float* lo_w1  = (const float*)d_in[18];
    const float* lo_b1  = (const float*)d_in[19];
    const float* lo_g1  = (const float*)d_in[20];
    const float* lo_bb1 = (const float*)d_in[21];
    const float* lo_w2  = (const float*)d_in[22];
    const float* lo_b2  = (const float*)d_in[23];
    const float* lo_g2  = (const float*)d_in[24];
    const float* lo_bb2 = (const float*)d_in[25];

    float* out0 = (float*)d_out;                       // (B,C,11,11)
    float* tk   = out0 + (size_t)BDIM_B * CDIM * SS;   // (1,C,11,11,3,3)

    // workspace layout (bytes, 64B-aligned chunks)
    char* ws = (char*)d_ws;
    size_t off = 0;
    auto alloc = [&](size_t bytes) { void* p = ws + off; off += (bytes + 63) & ~(size_t)63; return p; };
    u16*   Xb      = (u16*)alloc((size_t)MROWS * 512 * 2);
    u16*   Y1      = (u16*)alloc((size_t)MROWS * 1024 * 2);
    u16*   w1b     = (u16*)alloc((size_t)W1N * 2);
    u16*   w2b     = (u16*)alloc((size_t)W2N * 2);
    u16*   lw1b    = (u16*)alloc((size_t)L1N * 2);
    u16*   lw2b    = (u16*)alloc((size_t)L2N * 2);
    u16*   asum_b  = (u16*)alloc((size_t)128 * 1024 * 2);   // rows 121..127 unwritten
    u16*   a3b     = (u16*)alloc((size_t)128 * 1024 * 2);
    u16*   ts_pc   = (u16*)alloc((size_t)128 * 512 * 2);    // task_s (p,c) bf16
    float* dctT    = (float*)alloc((size_t)SS * 512 * 4);
    u16*   wcb     = (u16*)alloc((size_t)WCN * 2);          // w_conv bf16 16x512 (pad)
    float* ckbuf   = (float*)alloc((size_t)BDIM_B * CDIM * KK * 4);
    float* skbuf   = (float*)alloc((size_t)BDIM_B * SS * KK * 4);
    float* ck_t    = (float*)alloc((size_t)CDIM * KK * 4);
    float* sk_t    = (float*)alloc((size_t)SS * KK * 4);

    // --- prep: x transpose (16B stores) + weight casts + dct transpose ---
    hipLaunchKernelGGL(prep_combo, dim3(PREP_BLKS), dim3(256), 0, stream,
                       x, Xb, up_w1, up_w2, lo_w1, lo_w2, dct_w, w_conv,
                       w1b, w2b, lw1b, lw2b, dctT, wcb);

    // --- up path: ring-3 counted-vmcnt MFMA GEMMs (grid 968) ---
    hipLaunchKernelGGL((gemm_ring<1>), dim3(968), dim3(256), 0, stream,
                       Xb, w1b, up_b1, up_g1, up_bb1, (void*)Y1, 512, 1024);
    hipLaunchKernelGGL((gemm_ring<2>), dim3(968), dim3(256), 0, stream,
                       Y1, w2b, up_b2, up_g2, up_bb2, (void*)asum_b, 1024, 1024);

    // --- lo path: barrier-free 32-col GEMMs (32 + 16 blocks) ---
    hipLaunchKernelGGL((gemm_small<3>), dim3(32), dim3(256), 0, stream,
                       asum_b, lw1b, lo_b1, lo_g1, lo_bb1, a3b, 1024, 1024);
    hipLaunchKernelGGL((gemm_small<4>), dim3(16), dim3(256), 0, stream,
                       a3b, lw2b, lo_b2, lo_g2, lo_bb2, ts_pc, 1024, 512);

    // --- spatial MFMA GEMM + channel chain, one 251-block dispatch ---
    hipLaunchKernelGGL(spatial_ck_combo, dim3(122 + 129), dim3(256), 0, stream,
                       Xb, ts_pc, wcb, b_conv, g_sp, b_sp,
                       dctT, fc1, fc2, g_ch, b_ch,
                       skbuf, sk_t, ckbuf, ck_t);

    // --- final fused + task-kernel write, one dispatch ---
    hipLaunchKernelGGL(final_combo, dim3(FIN_BLKS), dim3(256), 0, stream,
                       x, skbuf, sk_t, ckbuf, ck_t, out0, tk);
}